// Round 10
// baseline (94.869 us; speedup 1.0000x reference)
//
#include <hip/hip_runtime.h>
#include <hip/hip_bf16.h>

#define NAG 8
#define BATCH 32768
#define DDIM 128
#define ADIM 64
#define HDIM 128

#define NJ1 11            // layer1 col tiles: 128 (W1) + 32 (Wc1) + 1 (Ws1) -> 176 cols
#define NJ2 8
#define NJ3 4
#define FB_L1 (NJ1*4)     // 44 frag blocks (44KB)
#define FB_L2 (NJ2*4)     // 32
#define FB_L3 (NJ3*4)     // 16
#define FB_B  (FB_L2+FB_L3)         // 48 frag blocks in bufB
#define FB_TOT (FB_L1+FB_L2+FB_L3)  // 92
#define WAGENT (FB_TOT*512)         // 47104 ushort per agent (92KB)

typedef __attribute__((ext_vector_type(8))) short bf16x8;
typedef __attribute__((ext_vector_type(4))) float f32x4;
typedef __attribute__((ext_vector_type(4))) unsigned int u32x4;

static __device__ __forceinline__ unsigned short f2bf(float f) {
  unsigned int u = __builtin_bit_cast(unsigned int, f);
  u += 0x7fffu + ((u >> 16) & 1u);          // RNE (inputs are finite)
  return (unsigned short)(u >> 16);
}

static __device__ __forceinline__ unsigned int cvt_pk_bf16(float a, float b) {
  unsigned int r;
  asm("v_cvt_pk_bf16_f32 %0, %1, %2" : "=v"(r) : "v"(a), "v"(b));
  return r;
}

// async global->LDS, 16B per lane; LDS dest = uniform base + lane*16 (linear)
static __device__ __forceinline__ void gload_lds16(const void* g, void* l) {
  __builtin_amdgcn_global_load_lds(
      (const __attribute__((address_space(1))) unsigned int*)g,
      (__attribute__((address_space(3))) unsigned int*)l, 16, 0, 0);
}

// ---------------- prep: f32 weights -> bf16 B-fragment-linear layout (proven) ----------------
// frag block fb=(j,kk): 512 bf16; element l*8+t = W[k = kk*32 + (l>>4)*8 + t][col = j*16 + (l&15)]
__global__ void __launch_bounds__(256)
prep_weights(const float* __restrict__ W1, const float* __restrict__ W2,
             const float* __restrict__ W3, const float* __restrict__ Wc1,
             const float* __restrict__ Ws1, const float* __restrict__ b1,
             const float* __restrict__ bc1, const float* __restrict__ bs1,
             unsigned short* __restrict__ wbuf, float* __restrict__ b1e)
{
  int tid = blockIdx.x * 256 + threadIdx.x;
  if (tid < NAG * WAGENT) {
    int agent = tid / WAGENT;
    int rem   = tid % WAGENT;
    int fb = rem >> 9;
    int li = rem & 511;
    int l = li >> 3, t = li & 7;
    int lr = l & 15, lg = l >> 4;
    float v = 0.0f;
    if (fb < FB_L1) {
      int j = fb >> 2, kk = fb & 3;
      int col = j*16 + lr, k = kk*32 + lg*8 + t;
      if (col < 128)       v = W1[((size_t)agent*128 + k)*128 + col];
      else if (col < 160)  v = Wc1[k*32 + (col-128)];
      else if (col == 160) v = Ws1[k];
    } else if (fb < FB_L1 + FB_L2) {
      int f = fb - FB_L1;
      int j = f >> 2, kk = f & 3;
      int col = j*16 + lr, k = kk*32 + lg*8 + t;
      v = W2[((size_t)agent*128 + k)*128 + col];
    } else {
      int f = fb - FB_L1 - FB_L2;
      int j = f >> 2, kk = f & 3;
      int col = j*16 + lr, k = kk*32 + lg*8 + t;
      v = W3[((size_t)agent*128 + k)*64 + col];
    }
    wbuf[tid] = f2bf(v);
  }
  if (tid < NAG * 176) {     // extended layer-1 bias: [b1 | bc1 | bs1 | 0]
    int agent = tid / 176, col = tid % 176;
    float v = 0.0f;
    if (col < 128)       v = b1[agent*128 + col];
    else if (col < 160)  v = bc1[col - 128];
    else if (col == 160) v = bs1[0];
    b1e[tid] = v;
  }
}

// ---------------- main: M=32/wave, 4 agents/block (y-split), LDS weights dbuf ----------------
// grid (128, 2): 256 blocks = 1/CU. 512 threads = 8 waves; wave w owns rows
// [blk.x*256 + w*32, +32) for agents [blk.y*4, +4). Per-wave B-fragment LDS reads
// amortized over 32 rows (halved vs M=16). Halves combine via atomicAdd into
// memset-zeroed out (exactly 2 commutative f32 contributors -> deterministic).
// LDS: bufA 44KB + bufB 48KB (agent dbuf via global_load_lds) + h 64KB = 156KB.
__global__ void __launch_bounds__(512, 1)
qatten_main(const float* __restrict__ states,
            const float* __restrict__ b2g, const float* __restrict__ b3g,
            const float* __restrict__ ws2p, const float* __restrict__ bs2p,
            const float* __restrict__ wc2g, const float* __restrict__ bc2p,
            const unsigned short* __restrict__ wbuf,
            const float* __restrict__ b1e,
            float* __restrict__ out)
{
  __shared__ __align__(16) unsigned short bufA[FB_L1*512];   // 44 KB
  __shared__ __align__(16) unsigned short bufB[FB_B*512];    // 48 KB
  __shared__ __align__(16) unsigned short hlds[8 * 4096];    // 64 KB

  const int tid  = threadIdx.x;
  const int wave = tid >> 6;
  const int lane = tid & 63;
  const int lr   = lane & 15;
  const int lg   = lane >> 4;
  const int row0 = blockIdx.x * 256 + wave * 32;
  const int abase = blockIdx.y * 4;

  unsigned short* hp = hlds + wave * 4096;   // this wave's 8KB h region [32][128] swizzled

  const float ws2  = ws2p[0];
  const float bs2v = bs2p[0];
  const float bc2v = bc2p[0];
  const float wc2a = wc2g[lr];
  const float wc2b = wc2g[16 + lr];

  const f32x4 zero4 = {0.f, 0.f, 0.f, 0.f};

  f32x4 out_acc[2][NJ3];
#pragma unroll
  for (int m = 0; m < 2; ++m)
#pragma unroll
    for (int j = 0; j < NJ3; ++j) out_acc[m][j] = zero4;

  // ---- prologue: stage first agent's weights; prefetch its states ----
  {
    const char* sA = (const char*)(wbuf + (size_t)abase * WAGENT);
    for (int c = wave; c < FB_L1; c += 8)
      gload_lds16(sA + c*1024 + lane*16, (char*)bufA + c*1024);
    const char* sB = sA + FB_L1*1024;
    for (int c = wave; c < FB_B; c += 8)
      gload_lds16(sB + c*1024 + lane*16, (char*)bufB + c*1024);
  }

  f32x4 sreg[16];           // raw states for the NEXT agent (2 per (m,kk))
  {
    const float* sb = states + ((size_t)abase * BATCH + row0) * DDIM;
#pragma unroll
    for (int m = 0; m < 2; ++m)
#pragma unroll
      for (int kk = 0; kk < 4; ++kk) {
        const float* p = sb + (m*16 + lr)*DDIM + kk*32 + lg*8;
        sreg[m*8 + kk*2]     = *(const f32x4*)p;
        sreg[m*8 + kk*2 + 1] = *(const f32x4*)(p + 4);
      }
  }
  __syncthreads();                    // vmcnt(0): first agent's weights published

  for (int a4 = 0; a4 < 4; ++a4) {
    const int a = abase + a4;

    // ---- biases (direct; small, L2-hot) ----
    float b1v[NJ1], b2v[NJ2], b3v[NJ3];
#pragma unroll
    for (int j = 0; j < NJ1; ++j) b1v[j] = b1e[a*176 + j*16 + lr];
#pragma unroll
    for (int j = 0; j < NJ2; ++j) b2v[j] = b2g[a*HDIM + j*16 + lr];
#pragma unroll
    for (int j = 0; j < NJ3; ++j) b3v[j] = b3g[a*ADIM + j*16 + lr];

    // ---- convert prefetched states -> A1 fragments (pure VALU) ----
    bf16x8 afr[2][4];
#pragma unroll
    for (int m = 0; m < 2; ++m)
#pragma unroll
      for (int kk = 0; kk < 4; ++kk) {
        f32x4 v0 = sreg[m*8 + kk*2], v1 = sreg[m*8 + kk*2 + 1];
        u32x4 w;
        w[0] = cvt_pk_bf16(v0[0], v0[1]);
        w[1] = cvt_pk_bf16(v0[2], v0[3]);
        w[2] = cvt_pk_bf16(v1[0], v1[1]);
        w[3] = cvt_pk_bf16(v1[2], v1[3]);
        afr[m][kk] = __builtin_bit_cast(bf16x8, w);
      }

    // ---- issue next agent's states (land under phases 1-3) ----
    if (a4 < 3) {
      const float* sb = states + ((size_t)(a+1) * BATCH + row0) * DDIM;
#pragma unroll
      for (int m = 0; m < 2; ++m)
#pragma unroll
        for (int kk = 0; kk < 4; ++kk) {
          const float* p = sb + (m*16 + lr)*DDIM + kk*32 + lg*8;
          sreg[m*8 + kk*2]     = *(const f32x4*)p;
          sreg[m*8 + kk*2 + 1] = *(const f32x4*)(p + 4);
        }
    }

    // ---- phase 1: L1 (j=0..7) + gates (j=8..10) from bufA, 2-deep pipelined ----
    f32x4 eacc[3][2];
    {
      bf16x8 pf[2][4];
#pragma unroll
      for (int kk = 0; kk < 4; ++kk)
        pf[0][kk] = *(const bf16x8*)&bufA[kk*512 + lane*8];
#pragma unroll
      for (int j = 0; j < 11; ++j) {
        if (j < 10) {
#pragma unroll
          for (int kk = 0; kk < 4; ++kk)
            pf[(j+1)&1][kk] = *(const bf16x8*)&bufA[((j+1)*4 + kk)*512 + lane*8];
        }
#pragma unroll
        for (int m = 0; m < 2; ++m) {
          f32x4 acc = zero4;
#pragma unroll
          for (int kk = 0; kk < 4; ++kk)
            acc = __builtin_amdgcn_mfma_f32_16x16x32_bf16(afr[m][kk], pf[j&1][kk], acc, 0, 0, 0);
          if (j < 8) {
#pragma unroll
            for (int r = 0; r < 4; ++r) {
              float hv = acc[r] + b1v[j];
              hv = hv > 0.f ? hv : 0.f;
              int row = m*16 + lg*4 + r;
              int bo = row*256 + (((j*16 + lr)*2) ^ ((row & 7) << 4));   // XOR swizzle
              *(unsigned short*)((char*)hp + bo) = f2bf(hv);
            }
          } else {
            eacc[j-8][m] = acc;
          }
        }
      }
    }

    // ---- gate & constraint scalars ----
    float scl[2][4], crow[2][4];
#pragma unroll
    for (int m = 0; m < 2; ++m)
#pragma unroll
      for (int r = 0; r < 4; ++r) {
        float c0 = eacc[0][m][r] + b1v[8];  c0 = c0 > 0.f ? c0 : 0.f;
        float c1 = eacc[1][m][r] + b1v[9];  c1 = c1 > 0.f ? c1 : 0.f;
        float cd = c0*wc2a + c1*wc2b;
        cd += __shfl_xor(cd, 1);
        cd += __shfl_xor(cd, 2);
        cd += __shfl_xor(cd, 4);
        cd += __shfl_xor(cd, 8);          // sum over 16 cols within lg-group
        crow[m][r] = cd + bc2v;
        float sp = eacc[2][m][r] + b1v[10];
        sp = __shfl(sp, lane & 48);       // broadcast col-160 (lr==0) value
        sp = sp > 0.f ? sp : 0.f;
        float s = ws2 * sp + bs2v;
        scl[m][r] = 1.f / (1.f + __expf(-s));
      }

    // ---- A2 fragments from own h region (hoisted BEFORE barrier: own-wave DS in-order) ----
#pragma unroll
    for (int m = 0; m < 2; ++m)
#pragma unroll
      for (int kk = 0; kk < 4; ++kk) {
        int row = m*16 + lr;
        int bo = row*256 + ((kk*64 + lg*16) ^ ((row & 7) << 4));
        afr[m][kk] = *(const bf16x8*)((char*)hp + bo);
      }

    __syncthreads();   // B1: all waves done reading bufA(a); bufB(a) published (vmcnt 0)

    // issue bufA <- L1(a+1): in flight under phases 2+3
    if (a4 < 3) {
      const char* sA = (const char*)(wbuf + (size_t)(a+1)*WAGENT);
      for (int c = wave; c < FB_L1; c += 8)
        gload_lds16(sA + c*1024 + lane*16, (char*)bufA + c*1024);
    }

    // ---- phase 2: L2 (j=0..7) from bufB, 2-deep pipelined ----
    {
      bf16x8 pf[2][4];
#pragma unroll
      for (int kk = 0; kk < 4; ++kk)
        pf[0][kk] = *(const bf16x8*)&bufB[kk*512 + lane*8];
#pragma unroll
      for (int j = 0; j < 8; ++j) {
        if (j < 7) {
#pragma unroll
          for (int kk = 0; kk < 4; ++kk)
            pf[(j+1)&1][kk] = *(const bf16x8*)&bufB[((j+1)*4 + kk)*512 + lane*8];
        }
#pragma unroll
        for (int m = 0; m < 2; ++m) {
          f32x4 acc = zero4;
#pragma unroll
          for (int kk = 0; kk < 4; ++kk)
            acc = __builtin_amdgcn_mfma_f32_16x16x32_bf16(afr[m][kk], pf[j&1][kk], acc, 0, 0, 0);
#pragma unroll
          for (int r = 0; r < 4; ++r) {
            float hv = acc[r] + b2v[j];
            hv = hv > 0.f ? hv : 0.f;
            int row = m*16 + lg*4 + r;
            int bo = row*256 + (((j*16 + lr)*2) ^ ((row & 7) << 4));
            *(unsigned short*)((char*)hp + bo) = f2bf(hv);   // overwrite h1 (A2 in regs)
          }
        }
      }
    }

    // ---- A3 fragments from h2 (own-wave DS in-order) ----
#pragma unroll
    for (int m = 0; m < 2; ++m)
#pragma unroll
      for (int kk = 0; kk < 4; ++kk) {
        int row = m*16 + lr;
        int bo = row*256 + ((kk*64 + lg*16) ^ ((row & 7) << 4));
        afr[m][kk] = *(const bf16x8*)((char*)hp + bo);
      }

    // ---- phase 3: L3 (j=0..3) from bufB, 2-deep; gated accumulate ----
    {
      bf16x8 pf[2][4];
#pragma unroll
      for (int kk = 0; kk < 4; ++kk)
        pf[0][kk] = *(const bf16x8*)&bufB[(FB_L2 + kk)*512 + lane*8];
#pragma unroll
      for (int j = 0; j < NJ3; ++j) {
        if (j < NJ3-1) {
#pragma unroll
          for (int kk = 0; kk < 4; ++kk)
            pf[(j+1)&1][kk] = *(const bf16x8*)&bufB[(FB_L2 + (j+1)*4 + kk)*512 + lane*8];
        }
#pragma unroll
        for (int m = 0; m < 2; ++m) {
          f32x4 acc = zero4;
#pragma unroll
          for (int kk = 0; kk < 4; ++kk)
            acc = __builtin_amdgcn_mfma_f32_16x16x32_bf16(afr[m][kk], pf[j&1][kk], acc, 0, 0, 0);
#pragma unroll
          for (int r = 0; r < 4; ++r)
            out_acc[m][j][r] += scl[m][r] * (acc[r] + b3v[j]) + crow[m][r];
        }
      }
    }

    __syncthreads();   // B2: all waves done reading bufB(a); bufA(a+1) published (vmcnt 0)

    // issue bufB <- L23(a+1): in flight under next agent's phase 1
    if (a4 < 3) {
      const char* sB = (const char*)(wbuf + (size_t)(a+1)*WAGENT + FB_L1*512);
      for (int c = wave; c < FB_B; c += 8)
        gload_lds16(sB + c*1024 + lane*16, (char*)bufB + c*1024);
    }
  }

  // ---- combine the two agent halves: atomicAdd (exactly 2 contributors, deterministic) ----
#pragma unroll
  for (int m = 0; m < 2; ++m)
#pragma unroll
    for (int j = 0; j < NJ3; ++j)
#pragma unroll
      for (int r = 0; r < 4; ++r) {
        size_t row = (size_t)row0 + m*16 + lg*4 + r;
        atomicAdd(&out[row*ADIM + j*16 + lr], out_acc[m][j][r] * 0.125f);
      }
}

extern "C" void kernel_launch(void* const* d_in, const int* in_sizes, int n_in,
                              void* d_out, int out_size, void* d_ws, size_t ws_size,
                              hipStream_t stream)
{
  const float* states = (const float*)d_in[0];
  const float* W1  = (const float*)d_in[1];
  const float* b1  = (const float*)d_in[2];
  const float* W2  = (const float*)d_in[3];
  const float* b2  = (const float*)d_in[4];
  const float* W3  = (const float*)d_in[5];
  const float* b3  = (const float*)d_in[6];
  const float* Ws1 = (const float*)d_in[13];
  const float* bs1 = (const float*)d_in[14];
  const float* Ws2 = (const float*)d_in[15];
  const float* bs2 = (const float*)d_in[16];
  const float* Wc1 = (const float*)d_in[17];
  const float* bc1 = (const float*)d_in[18];
  const float* Wc2 = (const float*)d_in[19];
  const float* bc2 = (const float*)d_in[20];

  unsigned short* wbuf = (unsigned short*)d_ws;
  float* b1e = (float*)((char*)d_ws + (size_t)NAG * WAGENT * 2);

  hipMemsetAsync(d_out, 0, (size_t)out_size * sizeof(float), stream);

  dim3 pb(256), pg((NAG * WAGENT + 255) / 256);
  prep_weights<<<pg, pb, 0, stream>>>(W1, W2, W3, Wc1, Ws1, b1, bc1, bs1, wbuf, b1e);

  dim3 mb(512), mg(BATCH / 256, 2);   // 256 blocks = 1/CU; 8 waves x 32 rows; 4 agents/block
  qatten_main<<<mg, mb, 0, stream>>>(states, b2, b3, Ws2, bs2, Wc2, bc2,
                                     wbuf, b1e, (float*)d_out);
}

// Round 11
// 73.869 us; speedup vs baseline: 1.2843x; 1.2843x over previous
//
#include <hip/hip_runtime.h>
#include <hip/hip_bf16.h>

#define NAG 8
#define BATCH 32768
#define DDIM 128
#define ADIM 64
#define HDIM 128

#define NJ1 11            // layer1 col tiles: 128 (W1) + 32 (Wc1) + 1 (Ws1) -> 176 cols
#define NJ2 8
#define NJ3 4
#define FB_L1 (NJ1*4)     // 44 frag blocks (44KB)
#define FB_L2 (NJ2*4)     // 32
#define FB_L3 (NJ3*4)     // 16
#define FB_B  (FB_L2+FB_L3)         // 48 frag blocks in bufB
#define FB_TOT (FB_L1+FB_L2+FB_L3)  // 92
#define WAGENT (FB_TOT*512)         // 47104 ushort per agent (92KB)

typedef __attribute__((ext_vector_type(8))) short bf16x8;
typedef __attribute__((ext_vector_type(4))) float f32x4;
typedef __attribute__((ext_vector_type(4))) unsigned int u32x4;

static __device__ __forceinline__ unsigned short f2bf(float f) {
  unsigned int u = __builtin_bit_cast(unsigned int, f);
  u += 0x7fffu + ((u >> 16) & 1u);          // RNE (inputs are finite)
  return (unsigned short)(u >> 16);
}

static __device__ __forceinline__ unsigned int cvt_pk_bf16(float a, float b) {
  unsigned int r;
  asm("v_cvt_pk_bf16_f32 %0, %1, %2" : "=v"(r) : "v"(a), "v"(b));
  return r;
}

// async global->LDS, 16B per lane; LDS dest = uniform base + lane*16 (linear)
static __device__ __forceinline__ void gload_lds16(const void* g, void* l) {
  __builtin_amdgcn_global_load_lds(
      (const __attribute__((address_space(1))) unsigned int*)g,
      (__attribute__((address_space(3))) unsigned int*)l, 16, 0, 0);
}

// ---------------- prep: f32 weights -> bf16 B-fragment-linear layout (proven) ----------------
// frag block fb=(j,kk): 512 bf16; element l*8+t = W[k = kk*32 + (l>>4)*8 + t][col = j*16 + (l&15)]
__global__ void __launch_bounds__(256)
prep_weights(const float* __restrict__ W1, const float* __restrict__ W2,
             const float* __restrict__ W3, const float* __restrict__ Wc1,
             const float* __restrict__ Ws1, const float* __restrict__ b1,
             const float* __restrict__ bc1, const float* __restrict__ bs1,
             unsigned short* __restrict__ wbuf, float* __restrict__ b1e)
{
  int tid = blockIdx.x * 256 + threadIdx.x;
  if (tid < NAG * WAGENT) {
    int agent = tid / WAGENT;
    int rem   = tid % WAGENT;
    int fb = rem >> 9;
    int li = rem & 511;
    int l = li >> 3, t = li & 7;
    int lr = l & 15, lg = l >> 4;
    float v = 0.0f;
    if (fb < FB_L1) {
      int j = fb >> 2, kk = fb & 3;
      int col = j*16 + lr, k = kk*32 + lg*8 + t;
      if (col < 128)       v = W1[((size_t)agent*128 + k)*128 + col];
      else if (col < 160)  v = Wc1[k*32 + (col-128)];
      else if (col == 160) v = Ws1[k];
    } else if (fb < FB_L1 + FB_L2) {
      int f = fb - FB_L1;
      int j = f >> 2, kk = f & 3;
      int col = j*16 + lr, k = kk*32 + lg*8 + t;
      v = W2[((size_t)agent*128 + k)*128 + col];
    } else {
      int f = fb - FB_L1 - FB_L2;
      int j = f >> 2, kk = f & 3;
      int col = j*16 + lr, k = kk*32 + lg*8 + t;
      v = W3[((size_t)agent*128 + k)*64 + col];
    }
    wbuf[tid] = f2bf(v);
  }
  if (tid < NAG * 176) {     // extended layer-1 bias: [b1 | bc1 | bs1 | 0]
    int agent = tid / 176, col = tid % 176;
    float v = 0.0f;
    if (col < 128)       v = b1[agent*128 + col];
    else if (col < 160)  v = bc1[col - 128];
    else if (col == 160) v = bs1[0];
    b1e[tid] = v;
  }
}

// ---------------- main: M=32/wave, 4 agents/block (y-split), register-trimmed ----------------
// grid (128, 2): 256 blocks = 1/CU. 512 threads = 8 waves; wave w owns rows
// [blk.x*256 + w*32, +32) for agents [blk.y*4, +4). B-fragment LDS reads amortized
// over 32 rows (halved per CU vs M=16). No states-prefetch (reg budget: 512-thread
// blocks cap at ~128 arch VGPRs); bias loads distributed into their phases.
// Halves combine via atomicAdd into memset-zeroed out (2 contributors, deterministic).
__global__ void __launch_bounds__(512, 1)
qatten_main(const float* __restrict__ states,
            const float* __restrict__ b2g, const float* __restrict__ b3g,
            const float* __restrict__ ws2p, const float* __restrict__ bs2p,
            const float* __restrict__ wc2g, const float* __restrict__ bc2p,
            const unsigned short* __restrict__ wbuf,
            const float* __restrict__ b1e,
            float* __restrict__ out)
{
  __shared__ __align__(16) unsigned short bufA[FB_L1*512];   // 44 KB
  __shared__ __align__(16) unsigned short bufB[FB_B*512];    // 48 KB
  __shared__ __align__(16) unsigned short hlds[8 * 4096];    // 64 KB

  const int tid  = threadIdx.x;
  const int wave = tid >> 6;
  const int lane = tid & 63;
  const int lr   = lane & 15;
  const int lg   = lane >> 4;
  const int row0 = blockIdx.x * 256 + wave * 32;
  const int abase = blockIdx.y * 4;

  unsigned short* hp = hlds + wave * 4096;   // this wave's 8KB h region [32][128] swizzled

  const float ws2  = ws2p[0];
  const float bs2v = bs2p[0];
  const float bc2v = bc2p[0];
  const float wc2a = wc2g[lr];
  const float wc2b = wc2g[16 + lr];

  const f32x4 zero4 = {0.f, 0.f, 0.f, 0.f};

  f32x4 out_acc[2][NJ3];
#pragma unroll
  for (int m = 0; m < 2; ++m)
#pragma unroll
    for (int j = 0; j < NJ3; ++j) out_acc[m][j] = zero4;

  // ---- prologue: stage first agent's weights ----
  {
    const char* sA = (const char*)(wbuf + (size_t)abase * WAGENT);
    for (int c = wave; c < FB_L1; c += 8)
      gload_lds16(sA + c*1024 + lane*16, (char*)bufA + c*1024);
    const char* sB = sA + FB_L1*1024;
    for (int c = wave; c < FB_B; c += 8)
      gload_lds16(sB + c*1024 + lane*16, (char*)bufB + c*1024);
  }
  __syncthreads();                    // vmcnt(0): first agent's weights published

  for (int a4 = 0; a4 < 4; ++a4) {
    const int a = abase + a4;

    // ---- A1 fragments direct from global states (load+convert interleaved) ----
    bf16x8 afr[2][4];
    {
      const float* sb = states + ((size_t)a * BATCH + row0) * DDIM;
#pragma unroll
      for (int m = 0; m < 2; ++m)
#pragma unroll
        for (int kk = 0; kk < 4; ++kk) {
          const float* p = sb + (m*16 + lr)*DDIM + kk*32 + lg*8;
          f32x4 v0 = *(const f32x4*)p;
          f32x4 v1 = *(const f32x4*)(p + 4);
          u32x4 w;
          w[0] = cvt_pk_bf16(v0[0], v0[1]);
          w[1] = cvt_pk_bf16(v0[2], v0[3]);
          w[2] = cvt_pk_bf16(v1[0], v1[1]);
          w[3] = cvt_pk_bf16(v1[2], v1[3]);
          afr[m][kk] = __builtin_bit_cast(bf16x8, w);
        }
    }

    // ---- phase 1: L1 (j=0..7) + gates (j=8..10) from bufA, 2-deep pipelined ----
    float b1v[NJ1];
#pragma unroll
    for (int j = 0; j < NJ1; ++j) b1v[j] = b1e[a*176 + j*16 + lr];

    f32x4 eacc[3][2];
    {
      bf16x8 pf[2][4];
#pragma unroll
      for (int kk = 0; kk < 4; ++kk)
        pf[0][kk] = *(const bf16x8*)&bufA[kk*512 + lane*8];
#pragma unroll
      for (int j = 0; j < 11; ++j) {
        if (j < 10) {
#pragma unroll
          for (int kk = 0; kk < 4; ++kk)
            pf[(j+1)&1][kk] = *(const bf16x8*)&bufA[((j+1)*4 + kk)*512 + lane*8];
        }
#pragma unroll
        for (int m = 0; m < 2; ++m) {
          f32x4 acc = zero4;
#pragma unroll
          for (int kk = 0; kk < 4; ++kk)
            acc = __builtin_amdgcn_mfma_f32_16x16x32_bf16(afr[m][kk], pf[j&1][kk], acc, 0, 0, 0);
          if (j < 8) {
#pragma unroll
            for (int r = 0; r < 4; ++r) {
              float hv = acc[r] + b1v[j];
              hv = hv > 0.f ? hv : 0.f;
              int row = m*16 + lg*4 + r;
              int bo = row*256 + (((j*16 + lr)*2) ^ ((row & 7) << 4));   // XOR swizzle
              *(unsigned short*)((char*)hp + bo) = f2bf(hv);
            }
          } else {
            eacc[j-8][m] = acc;
          }
        }
      }
    }

    // ---- gate & constraint scalars ----
    float scl[2][4], crow[2][4];
#pragma unroll
    for (int m = 0; m < 2; ++m)
#pragma unroll
      for (int r = 0; r < 4; ++r) {
        float c0 = eacc[0][m][r] + b1v[8];  c0 = c0 > 0.f ? c0 : 0.f;
        float c1 = eacc[1][m][r] + b1v[9];  c1 = c1 > 0.f ? c1 : 0.f;
        float cd = c0*wc2a + c1*wc2b;
        cd += __shfl_xor(cd, 1);
        cd += __shfl_xor(cd, 2);
        cd += __shfl_xor(cd, 4);
        cd += __shfl_xor(cd, 8);          // sum over 16 cols within lg-group
        crow[m][r] = cd + bc2v;
        float sp = eacc[2][m][r] + b1v[10];
        sp = __shfl(sp, lane & 48);       // broadcast col-160 (lr==0) value
        sp = sp > 0.f ? sp : 0.f;
        float s = ws2 * sp + bs2v;
        scl[m][r] = 1.f / (1.f + __expf(-s));
      }

    // ---- A2 fragments from own h region (before barrier: own-wave DS in-order) ----
#pragma unroll
    for (int m = 0; m < 2; ++m)
#pragma unroll
      for (int kk = 0; kk < 4; ++kk) {
        int row = m*16 + lr;
        int bo = row*256 + ((kk*64 + lg*16) ^ ((row & 7) << 4));
        afr[m][kk] = *(const bf16x8*)((char*)hp + bo);
      }

    __syncthreads();   // B1: all waves done reading bufA(a); bufB(a) published (vmcnt 0)

    // issue bufA <- L1(a+1): in flight under phases 2+3
    if (a4 < 3) {
      const char* sA = (const char*)(wbuf + (size_t)(a+1)*WAGENT);
      for (int c = wave; c < FB_L1; c += 8)
        gload_lds16(sA + c*1024 + lane*16, (char*)bufA + c*1024);
    }

    // ---- phase 2: L2 (j=0..7) from bufB, 2-deep pipelined ----
    {
      float b2v[NJ2];
#pragma unroll
      for (int j = 0; j < NJ2; ++j) b2v[j] = b2g[a*HDIM + j*16 + lr];
      bf16x8 pf[2][4];
#pragma unroll
      for (int kk = 0; kk < 4; ++kk)
        pf[0][kk] = *(const bf16x8*)&bufB[kk*512 + lane*8];
#pragma unroll
      for (int j = 0; j < 8; ++j) {
        if (j < 7) {
#pragma unroll
          for (int kk = 0; kk < 4; ++kk)
            pf[(j+1)&1][kk] = *(const bf16x8*)&bufB[((j+1)*4 + kk)*512 + lane*8];
        }
#pragma unroll
        for (int m = 0; m < 2; ++m) {
          f32x4 acc = zero4;
#pragma unroll
          for (int kk = 0; kk < 4; ++kk)
            acc = __builtin_amdgcn_mfma_f32_16x16x32_bf16(afr[m][kk], pf[j&1][kk], acc, 0, 0, 0);
#pragma unroll
          for (int r = 0; r < 4; ++r) {
            float hv = acc[r] + b2v[j];
            hv = hv > 0.f ? hv : 0.f;
            int row = m*16 + lg*4 + r;
            int bo = row*256 + (((j*16 + lr)*2) ^ ((row & 7) << 4));
            *(unsigned short*)((char*)hp + bo) = f2bf(hv);   // overwrite h1 (A2 in regs)
          }
        }
      }
    }

    // ---- A3 fragments from h2 (own-wave DS in-order) ----
#pragma unroll
    for (int m = 0; m < 2; ++m)
#pragma unroll
      for (int kk = 0; kk < 4; ++kk) {
        int row = m*16 + lr;
        int bo = row*256 + ((kk*64 + lg*16) ^ ((row & 7) << 4));
        afr[m][kk] = *(const bf16x8*)((char*)hp + bo);
      }

    // ---- phase 3: L3 (j=0..3) from bufB, 2-deep; gated accumulate ----
    {
      float b3v[NJ3];
#pragma unroll
      for (int j = 0; j < NJ3; ++j) b3v[j] = b3g[a*ADIM + j*16 + lr];
      bf16x8 pf[2][4];
#pragma unroll
      for (int kk = 0; kk < 4; ++kk)
        pf[0][kk] = *(const bf16x8*)&bufB[(FB_L2 + kk)*512 + lane*8];
#pragma unroll
      for (int j = 0; j < NJ3; ++j) {
        if (j < NJ3-1) {
#pragma unroll
          for (int kk = 0; kk < 4; ++kk)
            pf[(j+1)&1][kk] = *(const bf16x8*)&bufB[(FB_L2 + (j+1)*4 + kk)*512 + lane*8];
        }
#pragma unroll
        for (int m = 0; m < 2; ++m) {
          f32x4 acc = zero4;
#pragma unroll
          for (int kk = 0; kk < 4; ++kk)
            acc = __builtin_amdgcn_mfma_f32_16x16x32_bf16(afr[m][kk], pf[j&1][kk], acc, 0, 0, 0);
#pragma unroll
          for (int r = 0; r < 4; ++r)
            out_acc[m][j][r] += scl[m][r] * (acc[r] + b3v[j]) + crow[m][r];
        }
      }
    }

    __syncthreads();   // B2: all waves done reading bufB(a); bufA(a+1) published (vmcnt 0)

    // issue bufB <- L23(a+1): in flight under next agent's phase 1
    if (a4 < 3) {
      const char* sB = (const char*)(wbuf + (size_t)(a+1)*WAGENT + FB_L1*512);
      for (int c = wave; c < FB_B; c += 8)
        gload_lds16(sB + c*1024 + lane*16, (char*)bufB + c*1024);
    }
  }

  // ---- combine the two agent halves: atomicAdd (exactly 2 contributors, deterministic) ----
#pragma unroll
  for (int m = 0; m < 2; ++m)
#pragma unroll
    for (int j = 0; j < NJ3; ++j)
#pragma unroll
      for (int r = 0; r < 4; ++r) {
        size_t row = (size_t)row0 + m*16 + lg*4 + r;
        atomicAdd(&out[row*ADIM + j*16 + lr], out_acc[m][j][r] * 0.125f);
      }
}

extern "C" void kernel_launch(void* const* d_in, const int* in_sizes, int n_in,
                              void* d_out, int out_size, void* d_ws, size_t ws_size,
                              hipStream_t stream)
{
  const float* states = (const float*)d_in[0];
  const float* W1  = (const float*)d_in[1];
  const float* b1  = (const float*)d_in[2];
  const float* W2  = (const float*)d_in[3];
  const float* b2  = (const float*)d_in[4];
  const float* W3  = (const float*)d_in[5];
  const float* b3  = (const float*)d_in[6];
  const float* Ws1 = (const float*)d_in[13];
  const float* bs1 = (const float*)d_in[14];
  const float* Ws2 = (const float*)d_in[15];
  const float* bs2 = (const float*)d_in[16];
  const float* Wc1 = (const float*)d_in[17];
  const float* bc1 = (const float*)d_in[18];
  const float* Wc2 = (const float*)d_in[19];
  const float* bc2 = (const float*)d_in[20];

  unsigned short* wbuf = (unsigned short*)d_ws;
  float* b1e = (float*)((char*)d_ws + (size_t)NAG * WAGENT * 2);

  hipMemsetAsync(d_out, 0, (size_t)out_size * sizeof(float), stream);

  dim3 pb(256), pg((NAG * WAGENT + 255) / 256);
  prep_weights<<<pg, pb, 0, stream>>>(W1, W2, W3, Wc1, Ws1, b1, bc1, bs1, wbuf, b1e);

  dim3 mb(512), mg(BATCH / 256, 2);   // 256 blocks = 1/CU; 8 waves x 32 rows; 4 agents/block
  qatten_main<<<mg, mb, 0, stream>>>(states, b2, b3, Ws2, bs2, Wc2, bc2,
                                     wbuf, b1e, (float*)d_out);
}

// Round 12
// 61.501 us; speedup vs baseline: 1.5426x; 1.2011x over previous
//
#include <hip/hip_runtime.h>
#include <hip/hip_bf16.h>

#define NAG 8
#define BATCH 32768
#define DDIM 128
#define ADIM 64
#define HDIM 128

#define NJ1 11            // layer1 col tiles: 128 (W1) + 32 (Wc1) + 1 (Ws1) -> 176 cols
#define NJ2 8
#define NJ3 4
#define FB_L1 (NJ1*4)     // 44 frag blocks (44KB)
#define FB_L2 (NJ2*4)     // 32
#define FB_L3 (NJ3*4)     // 16
#define FB_B  (FB_L2+FB_L3)         // 48 frag blocks in L23 group
#define FB_TOT (FB_L1+FB_L2+FB_L3)  // 92
#define WAGENT (FB_TOT*512)         // 47104 ushort per agent (92KB)

typedef __attribute__((ext_vector_type(8))) short bf16x8;
typedef __attribute__((ext_vector_type(4))) float f32x4;
typedef __attribute__((ext_vector_type(4))) unsigned int u32x4;

static __device__ __forceinline__ unsigned short f2bf(float f) {
  unsigned int u = __builtin_bit_cast(unsigned int, f);
  u += 0x7fffu + ((u >> 16) & 1u);          // RNE (inputs are finite)
  return (unsigned short)(u >> 16);
}

static __device__ __forceinline__ unsigned int cvt_pk_bf16(float a, float b) {
  unsigned int r;
  asm("v_cvt_pk_bf16_f32 %0, %1, %2" : "=v"(r) : "v"(a), "v"(b));
  return r;
}

// async global->LDS, 16B per lane; LDS dest = uniform base + lane*16 (linear)
static __device__ __forceinline__ void gload_lds16(const void* g, void* l) {
  __builtin_amdgcn_global_load_lds(
      (const __attribute__((address_space(1))) unsigned int*)g,
      (__attribute__((address_space(3))) unsigned int*)l, 16, 0, 0);
}

// ---------------- prep: f32 weights -> bf16 B-fragment-linear layout (proven) ----------------
// frag block fb=(j,kk): 512 bf16; element l*8+t = W[k = kk*32 + (l>>4)*8 + t][col = j*16 + (l&15)]
__global__ void __launch_bounds__(256)
prep_weights(const float* __restrict__ W1, const float* __restrict__ W2,
             const float* __restrict__ W3, const float* __restrict__ Wc1,
             const float* __restrict__ Ws1, const float* __restrict__ b1,
             const float* __restrict__ bc1, const float* __restrict__ bs1,
             unsigned short* __restrict__ wbuf, float* __restrict__ b1e)
{
  int tid = blockIdx.x * 256 + threadIdx.x;
  if (tid < NAG * WAGENT) {
    int agent = tid / WAGENT;
    int rem   = tid % WAGENT;
    int fb = rem >> 9;
    int li = rem & 511;
    int l = li >> 3, t = li & 7;
    int lr = l & 15, lg = l >> 4;
    float v = 0.0f;
    if (fb < FB_L1) {
      int j = fb >> 2, kk = fb & 3;
      int col = j*16 + lr, k = kk*32 + lg*8 + t;
      if (col < 128)       v = W1[((size_t)agent*128 + k)*128 + col];
      else if (col < 160)  v = Wc1[k*32 + (col-128)];
      else if (col == 160) v = Ws1[k];
    } else if (fb < FB_L1 + FB_L2) {
      int f = fb - FB_L1;
      int j = f >> 2, kk = f & 3;
      int col = j*16 + lr, k = kk*32 + lg*8 + t;
      v = W2[((size_t)agent*128 + k)*128 + col];
    } else {
      int f = fb - FB_L1 - FB_L2;
      int j = f >> 2, kk = f & 3;
      int col = j*16 + lr, k = kk*32 + lg*8 + t;
      v = W3[((size_t)agent*128 + k)*64 + col];
    }
    wbuf[tid] = f2bf(v);
  }
  if (tid < NAG * 176) {     // extended layer-1 bias: [b1 | bc1 | bs1 | 0]
    int agent = tid / 176, col = tid % 176;
    float v = 0.0f;
    if (col < 128)       v = b1[agent*128 + col];
    else if (col < 160)  v = bc1[col - 128];
    else if (col == 160) v = bs1[0];
    b1e[tid] = v;
  }
}

// ---------------- main: 2 blocks/CU, single staged weight buffer, M=16/wave ----------------
// 512 blocks x 256 threads (4 waves), 2 blocks/CU (LDS 64KB, VGPR<=128 via (256,2)).
// Wave w owns rows [blk*64 + w*16, +16), loops all 8 agents (register accumulator,
// plain stores). Weights: ONE 48KB buffer, staged twice per agent (L1-group then
// L23-group) via global_load_lds; the within-block staging drains are covered by
// the co-resident sibling block (desynced barriers) — that's this round's lever.
__global__ void __launch_bounds__(256, 2)
qatten_main(const float* __restrict__ states,
            const float* __restrict__ b2g, const float* __restrict__ b3g,
            const float* __restrict__ ws2p, const float* __restrict__ bs2p,
            const float* __restrict__ wc2g, const float* __restrict__ bc2p,
            const unsigned short* __restrict__ wbuf,
            const float* __restrict__ b1e,
            float* __restrict__ out)
{
  __shared__ __align__(16) unsigned short bufW[FB_B*512];    // 48 KB (L1 uses first 44KB)
  __shared__ __align__(16) unsigned short hlds[4 * 2048];    // 16 KB

  const int tid  = threadIdx.x;
  const int wave = tid >> 6;
  const int lane = tid & 63;
  const int lr   = lane & 15;
  const int lg   = lane >> 4;
  const int row0 = blockIdx.x * 64 + wave * 16;

  unsigned short* hp = hlds + wave * 2048;   // this wave's 4KB h region

  const float ws2  = ws2p[0];
  const float bs2v = bs2p[0];
  const float bc2v = bc2p[0];
  const float wc2a = wc2g[lr];
  const float wc2b = wc2g[16 + lr];

  const f32x4 zero4 = {0.f, 0.f, 0.f, 0.f};

  f32x4 out_acc[NJ3];
#pragma unroll
  for (int j = 0; j < NJ3; ++j) out_acc[j] = zero4;

  // ---- prologue: stage agent-0 L1 weights; prefetch agent-0 states & biases ----
  {
    const char* sA = (const char*)wbuf;
    for (int c = wave; c < FB_L1; c += 4)
      gload_lds16(sA + c*1024 + lane*16, (char*)bufW + c*1024);
  }

  f32x4 sreg[8];            // raw states for the NEXT agent (2 per kk)
  float b1n[NJ1], b2n[NJ2], b3n[NJ3];
  {
    const float* sb = states + (size_t)row0 * DDIM;     // agent 0
#pragma unroll
    for (int kk = 0; kk < 4; ++kk) {
      const float* p = sb + lr*DDIM + kk*32 + lg*8;
      sreg[kk*2]   = *(const f32x4*)p;
      sreg[kk*2+1] = *(const f32x4*)(p + 4);
    }
#pragma unroll
    for (int j = 0; j < NJ1; ++j) b1n[j] = b1e[j*16 + lr];
#pragma unroll
    for (int j = 0; j < NJ2; ++j) b2n[j] = b2g[j*16 + lr];
#pragma unroll
    for (int j = 0; j < NJ3; ++j) b3n[j] = b3g[j*16 + lr];
  }
  __syncthreads();                    // vmcnt(0): agent-0 L1 weights published

  for (int a = 0; a < NAG; ++a) {
    // ---- consume prefetched biases ----
    float b1v[NJ1], b2v[NJ2], b3v[NJ3];
#pragma unroll
    for (int j = 0; j < NJ1; ++j) b1v[j] = b1n[j];
#pragma unroll
    for (int j = 0; j < NJ2; ++j) b2v[j] = b2n[j];
#pragma unroll
    for (int j = 0; j < NJ3; ++j) b3v[j] = b3n[j];

    // ---- convert prefetched states -> A1 fragments (pure VALU, no memory wait) ----
    bf16x8 afr[4];
#pragma unroll
    for (int kk = 0; kk < 4; ++kk) {
      f32x4 v0 = sreg[kk*2], v1 = sreg[kk*2+1];
      u32x4 w;
      w[0] = cvt_pk_bf16(v0[0], v0[1]);
      w[1] = cvt_pk_bf16(v0[2], v0[3]);
      w[2] = cvt_pk_bf16(v1[0], v1[1]);
      w[3] = cvt_pk_bf16(v1[2], v1[3]);
      afr[kk] = __builtin_bit_cast(bf16x8, w);
    }

    // ---- issue next agent's states loads (land under phases 1-3) ----
    if (a < NAG-1) {
      const float* sb = states + ((size_t)(a+1) * BATCH + row0) * DDIM;
#pragma unroll
      for (int kk = 0; kk < 4; ++kk) {
        const float* p = sb + lr*DDIM + kk*32 + lg*8;
        sreg[kk*2]   = *(const f32x4*)p;
        sreg[kk*2+1] = *(const f32x4*)(p + 4);
      }
    }

    // ---- phase 1: L1 (j=0..7) + gates (j=8..10) from bufW, 3-deep pipelined ----
    f32x4 eacc[3];
    {
      bf16x8 pf[3][4];
#pragma unroll
      for (int kk = 0; kk < 4; ++kk) {
        pf[0][kk] = *(const bf16x8*)&bufW[(0*4 + kk)*512 + lane*8];
        pf[1][kk] = *(const bf16x8*)&bufW[(1*4 + kk)*512 + lane*8];
      }
#pragma unroll
      for (int j = 0; j < 11; ++j) {
        if (j + 2 <= 10) {
#pragma unroll
          for (int kk = 0; kk < 4; ++kk)
            pf[(j+2)%3][kk] = *(const bf16x8*)&bufW[((j+2)*4 + kk)*512 + lane*8];
        }
        f32x4 acc = zero4;
#pragma unroll
        for (int kk = 0; kk < 4; ++kk)
          acc = __builtin_amdgcn_mfma_f32_16x16x32_bf16(afr[kk], pf[j%3][kk], acc, 0, 0, 0);
        if (j < 8) {
#pragma unroll
          for (int r = 0; r < 4; ++r) {
            float hv = acc[r] + b1v[j];
            hv = hv > 0.f ? hv : 0.f;
            int row = lg*4 + r;
            int bo = row*256 + (((j*16 + lr)*2) ^ ((row & 7) << 4));   // XOR swizzle
            *(unsigned short*)((char*)hp + bo) = f2bf(hv);
          }
        } else {
          eacc[j-8] = acc;
        }
      }
    }

    // ---- gate & constraint scalars ----
    float scl[4], crow[4];
#pragma unroll
    for (int r = 0; r < 4; ++r) {
      float c0 = eacc[0][r] + b1v[8];  c0 = c0 > 0.f ? c0 : 0.f;
      float c1 = eacc[1][r] + b1v[9];  c1 = c1 > 0.f ? c1 : 0.f;
      float cd = c0*wc2a + c1*wc2b;
      cd += __shfl_xor(cd, 1);
      cd += __shfl_xor(cd, 2);
      cd += __shfl_xor(cd, 4);
      cd += __shfl_xor(cd, 8);          // sum over 16 cols within lg-group
      crow[r] = cd + bc2v;
      float sp = eacc[2][r] + b1v[10];
      sp = __shfl(sp, lane & 48);       // broadcast col-160 (lr==0) value
      sp = sp > 0.f ? sp : 0.f;
      float s = ws2 * sp + bs2v;
      scl[r] = 1.f / (1.f + __expf(-s));
    }

    // ---- A2 fragments from own h region (before barrier: own-wave DS in-order) ----
#pragma unroll
    for (int kk = 0; kk < 4; ++kk) {
      int row = lr;
      int bo = row*256 + ((kk*64 + lg*16) ^ ((row & 7) << 4));
      afr[kk] = *(const bf16x8*)((char*)hp + bo);
    }

    __syncthreads();   // B1: all waves done reading L1 weights

    // issue stage: bufW <- L23(a); prefetch next-agent biases into the drain window
    {
      const char* sB = (const char*)(wbuf + (size_t)a*WAGENT + FB_L1*512);
      for (int c = wave; c < FB_B; c += 4)
        gload_lds16(sB + c*1024 + lane*16, (char*)bufW + c*1024);
    }
    if (a < NAG-1) {
#pragma unroll
      for (int j = 0; j < NJ1; ++j) b1n[j] = b1e[(a+1)*176 + j*16 + lr];
#pragma unroll
      for (int j = 0; j < NJ2; ++j) b2n[j] = b2g[(a+1)*HDIM + j*16 + lr];
#pragma unroll
      for (int j = 0; j < NJ3; ++j) b3n[j] = b3g[(a+1)*ADIM + j*16 + lr];
    }

    __syncthreads();   // B2: vmcnt(0) drain publishes L23(a)

    // ---- phase 2: L2 (j=0..7) from bufW blocks 0..31, 3-deep pipelined ----
    {
      bf16x8 pf[3][4];
#pragma unroll
      for (int kk = 0; kk < 4; ++kk) {
        pf[0][kk] = *(const bf16x8*)&bufW[(0*4 + kk)*512 + lane*8];
        pf[1][kk] = *(const bf16x8*)&bufW[(1*4 + kk)*512 + lane*8];
      }
#pragma unroll
      for (int j = 0; j < 8; ++j) {
        if (j + 2 <= 7) {
#pragma unroll
          for (int kk = 0; kk < 4; ++kk)
            pf[(j+2)%3][kk] = *(const bf16x8*)&bufW[((j+2)*4 + kk)*512 + lane*8];
        }
        f32x4 acc = zero4;
#pragma unroll
        for (int kk = 0; kk < 4; ++kk)
          acc = __builtin_amdgcn_mfma_f32_16x16x32_bf16(afr[kk], pf[j%3][kk], acc, 0, 0, 0);
#pragma unroll
        for (int r = 0; r < 4; ++r) {
          float hv = acc[r] + b2v[j];
          hv = hv > 0.f ? hv : 0.f;
          int row = lg*4 + r;
          int bo = row*256 + (((j*16 + lr)*2) ^ ((row & 7) << 4));
          *(unsigned short*)((char*)hp + bo) = f2bf(hv);   // overwrite h1 (A2 in regs)
        }
      }
    }

    // ---- A3 fragments from h2 (own-wave DS in-order) ----
#pragma unroll
    for (int kk = 0; kk < 4; ++kk) {
      int row = lr;
      int bo = row*256 + ((kk*64 + lg*16) ^ ((row & 7) << 4));
      afr[kk] = *(const bf16x8*)((char*)hp + bo);
    }

    // ---- phase 3: L3 (j=0..3) from bufW blocks 32..47, 2-deep; gated accumulate ----
    {
      bf16x8 pf[2][4];
#pragma unroll
      for (int kk = 0; kk < 4; ++kk)
        pf[0][kk] = *(const bf16x8*)&bufW[(FB_L2 + kk)*512 + lane*8];
#pragma unroll
      for (int j = 0; j < NJ3; ++j) {
        if (j < NJ3-1) {
#pragma unroll
          for (int kk = 0; kk < 4; ++kk)
            pf[(j+1)&1][kk] = *(const bf16x8*)&bufW[(FB_L2 + (j+1)*4 + kk)*512 + lane*8];
        }
        f32x4 acc = zero4;
#pragma unroll
        for (int kk = 0; kk < 4; ++kk)
          acc = __builtin_amdgcn_mfma_f32_16x16x32_bf16(afr[kk], pf[j&1][kk], acc, 0, 0, 0);
#pragma unroll
        for (int r = 0; r < 4; ++r)
          out_acc[j][r] += scl[r] * (acc[r] + b3v[j]) + crow[r];
      }
    }

    __syncthreads();   // B3: all waves done reading L23 weights

    // issue stage: bufW <- L1(a+1)
    if (a < NAG-1) {
      const char* sA = (const char*)(wbuf + (size_t)(a+1)*WAGENT);
      for (int c = wave; c < FB_L1; c += 4)
        gload_lds16(sA + c*1024 + lane*16, (char*)bufW + c*1024);
    }

    __syncthreads();   // B4: vmcnt(0) drain publishes L1(a+1)
  }

  // ---- final store: out = mean over agents (deterministic, no atomics) ----
#pragma unroll
  for (int j = 0; j < NJ3; ++j)
#pragma unroll
    for (int r = 0; r < 4; ++r) {
      size_t row = (size_t)row0 + lg*4 + r;
      out[row*ADIM + j*16 + lr] = out_acc[j][r] * 0.125f;
    }
}

extern "C" void kernel_launch(void* const* d_in, const int* in_sizes, int n_in,
                              void* d_out, int out_size, void* d_ws, size_t ws_size,
                              hipStream_t stream)
{
  const float* states = (const float*)d_in[0];
  const float* W1  = (const float*)d_in[1];
  const float* b1  = (const float*)d_in[2];
  const float* W2  = (const float*)d_in[3];
  const float* b2  = (const float*)d_in[4];
  const float* W3  = (const float*)d_in[5];
  const float* b3  = (const float*)d_in[6];
  const float* Ws1 = (const float*)d_in[13];
  const float* bs1 = (const float*)d_in[14];
  const float* Ws2 = (const float*)d_in[15];
  const float* bs2 = (const float*)d_in[16];
  const float* Wc1 = (const float*)d_in[17];
  const float* bc1 = (const float*)d_in[18];
  const float* Wc2 = (const float*)d_in[19];
  const float* bc2 = (const float*)d_in[20];

  unsigned short* wbuf = (unsigned short*)d_ws;
  float* b1e = (float*)((char*)d_ws + (size_t)NAG * WAGENT * 2);

  dim3 pb(256), pg((NAG * WAGENT + 255) / 256);
  prep_weights<<<pg, pb, 0, stream>>>(W1, W2, W3, Wc1, Ws1, b1, bc1, bs1, wbuf, b1e);

  dim3 mb(256), mg(BATCH / 64);   // 512 blocks = 2 per CU, 4 waves each
  qatten_main<<<mg, mb, 0, stream>>>(states, b2, b3, Ws2, bs2, Wc2, bc2,
                                     wbuf, b1e, (float*)d_out);
}